// Round 1
// baseline (147.769 us; speedup 1.0000x reference)
//
#include <hip/hip_runtime.h>
#include <math.h>

namespace {

constexpr int NL  = 100;   // history length
constexpr int NT  = 20;    // topics
constexpr int NDV = 100;   // vector dim
constexpr float KEPS = 1e-8f;

struct Ptrs {
  const int*   user;
  const float* hist_lda;
  const float* hist_vector;
  const float* hist_info;
  const float* hist_authority;
  const float* hist_participants;
  const float* hist_interact;
  const float* timeDelta;
  const float* item_lda;
  const float* item_vector;
  const float* item_info;
  const float* item_authority;
  const float* item_participants;
  const float* item_interact;
  const float* know_lda_pref;
  const float* know_vector_pref;
  const float* lda_gain_ref;
  const float* com_participant_pref;
  const float* td_g;        const float* td_u;
  const float* info_part_g; const float* info_part_u;
  const float* topic_g;     const float* topic_u;
  const float* content_g;   const float* content_u;
  const float* info_w_u;
  const float* inter_apart_g; const float* inter_apart_u;
  const float* auth_apart_g;  const float* auth_apart_u;
  const float* part_w_g;    const float* part_w_u;
  const float* inter_w_g;   const float* inter_w_u;
  const float* auth_w_g;    const float* auth_w_u;
  const float* xref_g;      const float* xref_u;
  const float* xlam_g;      const float* xlam_u;
  const float* xalpha_g;    const float* xalpha_u;
  const float* xbeta_g;     const float* xbeta_u;
  const float* fc1_w; const float* fc1_b;
  const float* fc2_w; const float* fc2_b;
};

// sc[] layout: 0 topic_w, 1 content_w, 2 info_w, 3 part_w, 4 inter_w, 5 auth_w,
//              6 xref, 7 lam, 8 alpha, 9 beta, 10 tdc,
//              11..13 info_part coef, 14..15 inter coef, 16..18 auth coef
__device__ __forceinline__ float total_gain_one(
    const float* __restrict__ lda_row, const float* __restrict__ vec_row,
    const float* __restrict__ info_row, const float* __restrict__ part_row,
    const float* __restrict__ inter_row, const float* __restrict__ auth_row,
    const float* u_lda, const float* u_vec, const float* u_part,
    const float* sc, const float* norms, float* lda_out /* nullable: stash row */)
{
  // --- lda cosine (len 20, rows 16B aligned) ---
  float lr[NT];
  #pragma unroll
  for (int i = 0; i < NT / 4; ++i) {
    float4 v = reinterpret_cast<const float4*>(lda_row)[i];
    lr[4*i+0] = v.x; lr[4*i+1] = v.y; lr[4*i+2] = v.z; lr[4*i+3] = v.w;
  }
  float dot_l = 0.f, nn_l = 0.f;
  #pragma unroll
  for (int t = 0; t < NT; ++t) { dot_l += u_lda[t] * lr[t]; nn_l += lr[t] * lr[t]; }
  if (lda_out) {
    #pragma unroll
    for (int t = 0; t < NT; ++t) lda_out[t] = lr[t];
  }
  float lda_gain = dot_l / fmaxf(norms[0] * sqrtf(nn_l), KEPS);

  // --- vector cosine (len 100) ---
  float dot_v = 0.f, nn_v = 0.f;
  #pragma unroll 5
  for (int i = 0; i < NDV / 4; ++i) {
    float4 v = reinterpret_cast<const float4*>(vec_row)[i];
    dot_v += u_vec[4*i+0] * v.x + u_vec[4*i+1] * v.y
           + u_vec[4*i+2] * v.z + u_vec[4*i+3] * v.w;
    nn_v  += v.x * v.x + v.y * v.y + v.z * v.z + v.w * v.w;
  }
  float vec_gain = dot_v / fmaxf(norms[1] * sqrtf(nn_v), KEPS);

  // --- participants cosine (len 20) ---
  float dot_p = 0.f, nn_p = 0.f;
  #pragma unroll
  for (int i = 0; i < NT / 4; ++i) {
    float4 v = reinterpret_cast<const float4*>(part_row)[i];
    dot_p += u_part[4*i+0] * v.x + u_part[4*i+1] * v.y
           + u_part[4*i+2] * v.z + u_part[4*i+3] * v.w;
    nn_p  += v.x * v.x + v.y * v.y + v.z * v.z + v.w * v.w;
  }
  float part_sim = dot_p / fmaxf(norms[2] * sqrtf(nn_p), KEPS);

  // --- linear gains ---
  float info_gain  = sc[11] * info_row[0]  + sc[12] * info_row[1] + sc[13] * info_row[2];
  float inter_gain = sc[14] * inter_row[0] + sc[15] * inter_row[1];
  float auth_gain  = sc[16] * auth_row[0]  + sc[17] * auth_row[1] + sc[18] * auth_row[2];

  float x = lda_gain  * sc[0] + vec_gain   * sc[1] + info_gain * sc[2]
          + part_sim  * sc[3] + inter_gain * sc[4] + auth_gain * sc[5]
          - sc[6];
  float xa  = fabsf(x);
  bool  pos = (x > 0.f);
  float e   = pos ? sc[8] : sc[9];
  float v   = powf(xa, e);
  return pos ? v : -sc[7] * v;
}

__global__ __launch_bounds__(128)
void fused_fwd(Ptrs p, float* __restrict__ out)
{
  const int b   = blockIdx.x;
  const int tid = threadIdx.x;

  __shared__ float u_vec[NDV];
  __shared__ float u_lda[NT], u_part[NT], gref[NT];
  __shared__ float sc[19];
  __shared__ float norms[3];
  __shared__ float gw_s[NL];
  __shared__ float lda_s[NL][NT + 1];
  __shared__ float htop[NT];
  __shared__ float feat_s[3 * NT];
  __shared__ float hpart[NT];
  __shared__ float cg_s;

  const int u = p.user[b];

  // ---- stage per-user data ----
  for (int i = tid; i < NDV; i += blockDim.x)
    u_vec[i] = p.know_vector_pref[(size_t)u * NDV + i];
  if (tid < NT) {
    u_lda[tid]  = p.know_lda_pref[u * NT + tid];
    u_part[tid] = p.com_participant_pref[u * NT + tid];
    gref[tid]   = p.lda_gain_ref[u * NT + tid];
  }
  if (tid == 0) {
    sc[0]  = p.topic_g[0]   + p.topic_u[u];
    sc[1]  = p.content_g[0] + p.content_u[u];
    sc[2]  = p.info_w_u[0]  + p.info_w_u[u];   // faithful quirk: row 0 + user's row
    sc[3]  = p.part_w_g[0]  + p.part_w_u[u];
    sc[4]  = p.inter_w_g[0] + p.inter_w_u[u];
    sc[5]  = p.auth_w_g[0]  + p.auth_w_u[u];
    sc[6]  = p.xref_g[0]    + p.xref_u[u];
    sc[7]  = p.xlam_g[0]    + p.xlam_u[u];
    sc[8]  = p.xalpha_g[0]  + p.xalpha_u[u];
    sc[9]  = p.xbeta_g[0]   + p.xbeta_u[u];
    sc[10] = p.td_g[0]      + p.td_u[u];
    sc[11] = p.info_part_g[0] + p.info_part_u[u * 3 + 0];
    sc[12] = p.info_part_g[1] + p.info_part_u[u * 3 + 1];
    sc[13] = p.info_part_g[2] + p.info_part_u[u * 3 + 2];
    sc[14] = p.inter_apart_g[0] + p.inter_apart_u[u * 2 + 0];
    sc[15] = p.inter_apart_g[1] + p.inter_apart_u[u * 2 + 1];
    sc[16] = p.auth_apart_g[0] + p.auth_apart_u[u * 3 + 0];
    sc[17] = p.auth_apart_g[1] + p.auth_apart_u[u * 3 + 1];
    sc[18] = p.auth_apart_g[2] + p.auth_apart_u[u * 3 + 2];
  }
  __syncthreads();

  // ---- norms of the three preference vectors ----
  if (tid == 0) {
    float s = 0.f;
    #pragma unroll
    for (int t = 0; t < NT; ++t) s += u_lda[t] * u_lda[t];
    norms[0] = sqrtf(s);
    s = 0.f;
    #pragma unroll
    for (int t = 0; t < NT; ++t) s += u_part[t] * u_part[t];
    norms[2] = sqrtf(s);
  }
  if (tid == 1) {
    float s = 0.f;
    for (int i = 0; i < NDV; ++i) s += u_vec[i] * u_vec[i];
    norms[1] = sqrtf(s);
  }
  __syncthreads();

  // ---- per-history-step gain (thread l handles step l) ----
  if (tid < NL) {
    const int l = tid;
    const size_t bl = (size_t)b * NL + l;
    float g = total_gain_one(
        p.hist_lda          + bl * NT,
        p.hist_vector       + bl * NDV,
        p.hist_info         + bl * 3,
        p.hist_participants + bl * NT,
        p.hist_interact     + bl * 2,
        p.hist_authority    + bl * 3,
        u_lda, u_vec, u_part, sc, norms, &lda_s[l][0]);
    float w = expf(-p.timeDelta[bl] * sc[10]);
    gw_s[l] = g * w;
  }
  __syncthreads();

  // ---- hist_topic reduction (wave 0) ∥ current-item gain (wave 1) ----
  if (tid < NT) {
    float acc = 0.f;
    for (int l = 0; l < NL; ++l) acc += lda_s[l][tid] * gw_s[l];
    htop[tid] = acc;
  }
  if (tid == 100) {
    cg_s = total_gain_one(
        p.item_lda          + (size_t)b * NT,
        p.item_vector       + (size_t)b * NDV,
        p.item_info         + (size_t)b * 3,
        p.item_participants + (size_t)b * NT,
        p.item_interact     + (size_t)b * 2,
        p.item_authority    + (size_t)b * 3,
        u_lda, u_vec, u_part, sc, norms, nullptr);
  }
  __syncthreads();

  // ---- features ----
  if (tid < NT) {
    float diff = gref[tid] - htop[tid];
    float curr = cg_s * p.item_lda[(size_t)b * NT + tid];
    feat_s[tid]          = diff;
    feat_s[NT + tid]     = diff * curr;
    feat_s[2 * NT + tid] = curr;
  }
  __syncthreads();

  // ---- fc1 + fc2 weight ----
  if (tid < NT) {
    float acc = p.fc1_b[tid];
    const float* wrow = p.fc1_w + tid * 60;
    #pragma unroll 4
    for (int k = 0; k < 60; ++k) acc += wrow[k] * feat_s[k];
    hpart[tid] = acc * p.fc2_w[tid];
  }
  __syncthreads();

  if (tid == 0) {
    float s = p.fc2_b[0];
    #pragma unroll
    for (int j = 0; j < NT; ++j) s += hpart[j];
    out[b] = s;
  }
}

} // namespace

extern "C" void kernel_launch(void* const* d_in, const int* in_sizes, int n_in,
                              void* d_out, int out_size, void* d_ws, size_t ws_size,
                              hipStream_t stream) {
  Ptrs p;
  p.user              = (const int*)  d_in[0];
  p.hist_lda          = (const float*)d_in[1];
  p.hist_vector       = (const float*)d_in[2];
  p.hist_info         = (const float*)d_in[3];
  p.hist_authority    = (const float*)d_in[4];
  p.hist_participants = (const float*)d_in[5];
  p.hist_interact     = (const float*)d_in[6];
  p.timeDelta         = (const float*)d_in[7];
  p.item_lda          = (const float*)d_in[8];
  p.item_vector       = (const float*)d_in[9];
  p.item_info         = (const float*)d_in[10];
  p.item_authority    = (const float*)d_in[11];
  p.item_participants = (const float*)d_in[12];
  p.item_interact     = (const float*)d_in[13];
  p.know_lda_pref     = (const float*)d_in[14];
  p.know_vector_pref  = (const float*)d_in[15];
  p.lda_gain_ref      = (const float*)d_in[16];
  p.com_participant_pref = (const float*)d_in[17];
  p.td_g   = (const float*)d_in[18];  p.td_u   = (const float*)d_in[19];
  p.info_part_g = (const float*)d_in[20]; p.info_part_u = (const float*)d_in[21];
  p.topic_g   = (const float*)d_in[22]; p.topic_u   = (const float*)d_in[23];
  p.content_g = (const float*)d_in[24]; p.content_u = (const float*)d_in[25];
  p.info_w_u  = (const float*)d_in[26];
  p.inter_apart_g = (const float*)d_in[27]; p.inter_apart_u = (const float*)d_in[28];
  p.auth_apart_g  = (const float*)d_in[29]; p.auth_apart_u  = (const float*)d_in[30];
  p.part_w_g  = (const float*)d_in[31]; p.part_w_u  = (const float*)d_in[32];
  p.inter_w_g = (const float*)d_in[33]; p.inter_w_u = (const float*)d_in[34];
  p.auth_w_g  = (const float*)d_in[35]; p.auth_w_u  = (const float*)d_in[36];
  p.xref_g   = (const float*)d_in[37]; p.xref_u   = (const float*)d_in[38];
  p.xlam_g   = (const float*)d_in[39]; p.xlam_u   = (const float*)d_in[40];
  p.xalpha_g = (const float*)d_in[41]; p.xalpha_u = (const float*)d_in[42];
  p.xbeta_g  = (const float*)d_in[43]; p.xbeta_u  = (const float*)d_in[44];
  p.fc1_w = (const float*)d_in[45]; p.fc1_b = (const float*)d_in[46];
  p.fc2_w = (const float*)d_in[47]; p.fc2_b = (const float*)d_in[48];

  float* out = (float*)d_out;
  const int nblocks = in_sizes[0];  // B = 8192
  fused_fwd<<<nblocks, 128, 0, stream>>>(p, out);
}

// Round 2
// 143.698 us; speedup vs baseline: 1.0283x; 1.0283x over previous
//
#include <hip/hip_runtime.h>
#include <math.h>

namespace {

constexpr int NL  = 100;   // history length
constexpr int NT  = 20;    // topics
constexpr int NDV = 100;   // vector dim
constexpr float KEPS = 1e-8f;

struct Ptrs {
  const int*   user;
  const float* hist_lda;
  const float* hist_vector;
  const float* hist_info;
  const float* hist_authority;
  const float* hist_participants;
  const float* hist_interact;
  const float* timeDelta;
  const float* item_lda;
  const float* item_vector;
  const float* item_info;
  const float* item_authority;
  const float* item_participants;
  const float* item_interact;
  const float* know_lda_pref;
  const float* know_vector_pref;
  const float* lda_gain_ref;
  const float* com_participant_pref;
  const float* td_g;        const float* td_u;
  const float* info_part_g; const float* info_part_u;
  const float* topic_g;     const float* topic_u;
  const float* content_g;   const float* content_u;
  const float* info_w_u;
  const float* inter_apart_g; const float* inter_apart_u;
  const float* auth_apart_g;  const float* auth_apart_u;
  const float* part_w_g;    const float* part_w_u;
  const float* inter_w_g;   const float* inter_w_u;
  const float* auth_w_g;    const float* auth_w_u;
  const float* xref_g;      const float* xref_u;
  const float* xlam_g;      const float* xlam_u;
  const float* xalpha_g;    const float* xalpha_u;
  const float* xbeta_g;     const float* xbeta_u;
  const float* fc1_w; const float* fc1_b;
  const float* fc2_w; const float* fc2_b;
};

// sc[] layout: 0 topic_w, 1 content_w, 2 info_w, 3 part_w, 4 inter_w, 5 auth_w,
//              6 xref, 7 lam, 8 alpha, 9 beta, 10 tdc,
//              11..13 info coef, 14..15 inter coef, 16..18 auth coef
__global__ __launch_bounds__(256)
void fused_fwd(Ptrs p, float* __restrict__ out)
{
  const int b   = blockIdx.x;
  const int tid = threadIdx.x;

  // 101 rows everywhere: rows 0..99 = history, row 100 = current item.
  __shared__ __align__(16) float lda_s [101 * NT];      // 2020
  __shared__ __align__(16) float part_s[101 * NT];      // 2020
  __shared__ __align__(16) float info_s [304];          // 101*3 (+pad)
  __shared__ __align__(16) float auth_s [304];
  __shared__ __align__(16) float inter_s[202];
  __shared__ __align__(16) float td_s   [100];
  __shared__ __align__(16) float u_vec  [NDV];
  __shared__ __align__(16) float u_lda[NT], u_part[NT], gref[NT];
  __shared__ float dotv_s[101], nnv_s[101];
  __shared__ float sc[19];
  __shared__ float norms[3];
  __shared__ float gw_s[NL];
  __shared__ float cg_s;
  __shared__ float partial_s[5][NT];
  __shared__ float feat_s[3 * NT];

  const int u = p.user[b];

  // ================= STAGING (all coalesced float4) =================
  {
    const float4* sl = (const float4*)(p.hist_lda          + (size_t)b * NL * NT);
    const float4* sp = (const float4*)(p.hist_participants + (size_t)b * NL * NT);
    float4* dl = (float4*)lda_s;
    float4* dp = (float4*)part_s;
    for (int i = tid; i < 500; i += 256) { dl[i] = sl[i]; dp[i] = sp[i]; }
  }
  if (tid < 75)
    ((float4*)info_s)[tid]        = ((const float4*)(p.hist_info      + (size_t)b * 300))[tid];
  else if (tid < 150)
    ((float4*)auth_s)[tid - 75]   = ((const float4*)(p.hist_authority + (size_t)b * 300))[tid - 75];
  else if (tid < 200)
    ((float4*)inter_s)[tid - 150] = ((const float4*)(p.hist_interact  + (size_t)b * 200))[tid - 150];
  else if (tid < 225)
    ((float4*)td_s)[tid - 200]    = ((const float4*)(p.timeDelta      + (size_t)b * 100))[tid - 200];
  else if (tid < 250)
    ((float4*)u_vec)[tid - 225]   = ((const float4*)(p.know_vector_pref + (size_t)u * NDV))[tid - 225];

  if (tid < 5)
    ((float4*)u_lda)[tid]         = ((const float4*)(p.know_lda_pref        + (size_t)u * NT))[tid];
  else if (tid < 10)
    ((float4*)u_part)[tid - 5]    = ((const float4*)(p.com_participant_pref + (size_t)u * NT))[tid - 5];
  else if (tid < 15)
    ((float4*)gref)[tid - 10]     = ((const float4*)(p.lda_gain_ref         + (size_t)u * NT))[tid - 10];
  else if (tid < 20)
    ((float4*)lda_s)[500 + tid - 15]  = ((const float4*)(p.item_lda          + (size_t)b * NT))[tid - 15];
  else if (tid < 25)
    ((float4*)part_s)[500 + tid - 20] = ((const float4*)(p.item_participants + (size_t)b * NT))[tid - 20];
  else if (tid < 28)
    info_s[300 + tid - 25]  = p.item_info[(size_t)b * 3 + tid - 25];
  else if (tid < 31)
    auth_s[300 + tid - 28]  = p.item_authority[(size_t)b * 3 + tid - 28];
  else if (tid < 33)
    inter_s[200 + tid - 31] = p.item_interact[(size_t)b * 2 + tid - 31];
  else if (tid == 33) {
    sc[0]  = p.topic_g[0]   + p.topic_u[u];
    sc[1]  = p.content_g[0] + p.content_u[u];
    sc[2]  = p.info_w_u[0]  + p.info_w_u[u];   // faithful quirk: row 0 + user's row
    sc[3]  = p.part_w_g[0]  + p.part_w_u[u];
    sc[4]  = p.inter_w_g[0] + p.inter_w_u[u];
    sc[5]  = p.auth_w_g[0]  + p.auth_w_u[u];
    sc[6]  = p.xref_g[0]    + p.xref_u[u];
    sc[7]  = p.xlam_g[0]    + p.xlam_u[u];
    sc[8]  = p.xalpha_g[0]  + p.xalpha_u[u];
    sc[9]  = p.xbeta_g[0]   + p.xbeta_u[u];
    sc[10] = p.td_g[0]      + p.td_u[u];
    sc[11] = p.info_part_g[0] + p.info_part_u[u * 3 + 0];
    sc[12] = p.info_part_g[1] + p.info_part_u[u * 3 + 1];
    sc[13] = p.info_part_g[2] + p.info_part_u[u * 3 + 2];
    sc[14] = p.inter_apart_g[0] + p.inter_apart_u[u * 2 + 0];
    sc[15] = p.inter_apart_g[1] + p.inter_apart_u[u * 2 + 1];
    sc[16] = p.auth_apart_g[0] + p.auth_apart_u[u * 3 + 0];
    sc[17] = p.auth_apart_g[1] + p.auth_apart_u[u * 3 + 1];
    sc[18] = p.auth_apart_g[2] + p.auth_apart_u[u * 3 + 2];
  }
  __syncthreads();

  // ============ PHASE A: vector cosine, lane-parallel along DV ============
  // Half-wave (32 lanes) per row; lanes 0..24 each hold one float4 of the row.
  {
    const int c      = tid & 31;    // lane within half-wave
    const int rowoff = tid >> 5;    // 0..7
    float4 uv = make_float4(0.f, 0.f, 0.f, 0.f);
    if (c < 25) uv = ((const float4*)u_vec)[c];
    const float4* hv4 = (const float4*)(p.hist_vector + (size_t)b * NL * NDV);
    const float4* iv4 = (const float4*)(p.item_vector + (size_t)b * NDV);
    #pragma unroll 4
    for (int i = 0; i < 13; ++i) {
      const int r = i * 8 + rowoff;
      float d = 0.f, n = 0.f;
      if (c < 25 && r <= 100) {
        float4 v = (r < NL) ? hv4[r * 25 + c] : iv4[c];
        d = uv.x * v.x + uv.y * v.y + uv.z * v.z + uv.w * v.w;
        n = v.x * v.x + v.y * v.y + v.z * v.z + v.w * v.w;
      }
      #pragma unroll
      for (int m = 1; m < 32; m <<= 1) {
        d += __shfl_xor(d, m);
        n += __shfl_xor(n, m);
      }
      if (c == 0 && r <= 100) { dotv_s[r] = d; nnv_s[r] = n; }
    }
  }

  // preference-vector norms (overlapped tail work)
  if (tid < 32) {
    float s = 0.f;
    if (tid < 25) {
      float4 v = ((const float4*)u_vec)[tid];
      s = v.x * v.x + v.y * v.y + v.z * v.z + v.w * v.w;
    }
    #pragma unroll
    for (int m = 1; m < 32; m <<= 1) s += __shfl_xor(s, m);
    if (tid == 0) norms[1] = sqrtf(s);
  } else if (tid == 64) {
    float s = 0.f;
    #pragma unroll
    for (int t = 0; t < NT; ++t) s += u_lda[t] * u_lda[t];
    norms[0] = sqrtf(s);
  } else if (tid == 65) {
    float s = 0.f;
    #pragma unroll
    for (int t = 0; t < NT; ++t) s += u_part[t] * u_part[t];
    norms[2] = sqrtf(s);
  }
  __syncthreads();

  // ============ PHASE B: per-row gains (rows 0..99 hist, 100 item) ============
  if (tid <= 100) {
    const int l = tid;
    const float4* lr4 = (const float4*)&lda_s [l * NT];
    const float4* pr4 = (const float4*)&part_s[l * NT];
    float dot_l = 0.f, nn_l = 0.f, dot_p = 0.f, nn_p = 0.f;
    #pragma unroll
    for (int i = 0; i < 5; ++i) {
      float4 a = lr4[i];
      float4 q = pr4[i];
      dot_l += u_lda[4*i+0] * a.x + u_lda[4*i+1] * a.y + u_lda[4*i+2] * a.z + u_lda[4*i+3] * a.w;
      nn_l  += a.x * a.x + a.y * a.y + a.z * a.z + a.w * a.w;
      dot_p += u_part[4*i+0] * q.x + u_part[4*i+1] * q.y + u_part[4*i+2] * q.z + u_part[4*i+3] * q.w;
      nn_p  += q.x * q.x + q.y * q.y + q.z * q.z + q.w * q.w;
    }
    float lda_gain = dot_l / fmaxf(norms[0] * sqrtf(nn_l), KEPS);
    float part_sim = dot_p / fmaxf(norms[2] * sqrtf(nn_p), KEPS);
    float vec_gain = dotv_s[l] / fmaxf(norms[1] * sqrtf(nnv_s[l]), KEPS);
    float info_gain  = sc[11] * info_s[l*3+0] + sc[12] * info_s[l*3+1] + sc[13] * info_s[l*3+2];
    float inter_gain = sc[14] * inter_s[l*2+0] + sc[15] * inter_s[l*2+1];
    float auth_gain  = sc[16] * auth_s[l*3+0] + sc[17] * auth_s[l*3+1] + sc[18] * auth_s[l*3+2];

    float x = lda_gain  * sc[0] + vec_gain   * sc[1] + info_gain * sc[2]
            + part_sim  * sc[3] + inter_gain * sc[4] + auth_gain * sc[5]
            - sc[6];
    float xa  = fabsf(x);
    bool  pos = (x > 0.f);
    float v   = powf(xa, pos ? sc[8] : sc[9]);
    float gg  = pos ? v : -sc[7] * v;
    if (l < NL) gw_s[l] = gg * expf(-td_s[l] * sc[10]);
    else        cg_s   = gg;
  }
  __syncthreads();

  // ============ PHASE C: hist_topic partial reduction (5-way split) ============
  if (tid < 100) {
    const int g = tid / NT, t = tid % NT;
    const float* base = &lda_s[g * NT * NT + t];
    const float* gw   = &gw_s[g * NT];
    float acc = 0.f;
    #pragma unroll
    for (int l = 0; l < NT; ++l) acc += base[l * NT] * gw[l];
    partial_s[g][t] = acc;
  }
  __syncthreads();

  // ============ PHASE D: features ============
  if (tid < NT) {
    float htop = partial_s[0][tid] + partial_s[1][tid] + partial_s[2][tid]
               + partial_s[3][tid] + partial_s[4][tid];
    float diff = gref[tid] - htop;
    float curr = cg_s * lda_s[100 * NT + tid];
    feat_s[tid]          = diff;
    feat_s[NT + tid]     = diff * curr;
    feat_s[2 * NT + tid] = curr;
  }
  __syncthreads();

  // ============ PHASE E: fc1 + fc2 (wave-0 reduce) ============
  if (tid < 32) {
    float hp = 0.f;
    if (tid < NT) {
      float acc = p.fc1_b[tid];
      const float* wrow = p.fc1_w + tid * 60;
      #pragma unroll
      for (int k = 0; k < 60; ++k) acc += wrow[k] * feat_s[k];
      hp = acc * p.fc2_w[tid];
    }
    #pragma unroll
    for (int m = 1; m < 32; m <<= 1) hp += __shfl_xor(hp, m);
    if (tid == 0) out[b] = hp + p.fc2_b[0];
  }
}

} // namespace

extern "C" void kernel_launch(void* const* d_in, const int* in_sizes, int n_in,
                              void* d_out, int out_size, void* d_ws, size_t ws_size,
                              hipStream_t stream) {
  Ptrs p;
  p.user              = (const int*)  d_in[0];
  p.hist_lda          = (const float*)d_in[1];
  p.hist_vector       = (const float*)d_in[2];
  p.hist_info         = (const float*)d_in[3];
  p.hist_authority    = (const float*)d_in[4];
  p.hist_participants = (const float*)d_in[5];
  p.hist_interact     = (const float*)d_in[6];
  p.timeDelta         = (const float*)d_in[7];
  p.item_lda          = (const float*)d_in[8];
  p.item_vector       = (const float*)d_in[9];
  p.item_info         = (const float*)d_in[10];
  p.item_authority    = (const float*)d_in[11];
  p.item_participants = (const float*)d_in[12];
  p.item_interact     = (const float*)d_in[13];
  p.know_lda_pref     = (const float*)d_in[14];
  p.know_vector_pref  = (const float*)d_in[15];
  p.lda_gain_ref      = (const float*)d_in[16];
  p.com_participant_pref = (const float*)d_in[17];
  p.td_g   = (const float*)d_in[18];  p.td_u   = (const float*)d_in[19];
  p.info_part_g = (const float*)d_in[20]; p.info_part_u = (const float*)d_in[21];
  p.topic_g   = (const float*)d_in[22]; p.topic_u   = (const float*)d_in[23];
  p.content_g = (const float*)d_in[24]; p.content_u = (const float*)d_in[25];
  p.info_w_u  = (const float*)d_in[26];
  p.inter_apart_g = (const float*)d_in[27]; p.inter_apart_u = (const float*)d_in[28];
  p.auth_apart_g  = (const float*)d_in[29]; p.auth_apart_u  = (const float*)d_in[30];
  p.part_w_g  = (const float*)d_in[31]; p.part_w_u  = (const float*)d_in[32];
  p.inter_w_g = (const float*)d_in[33]; p.inter_w_u = (const float*)d_in[34];
  p.auth_w_g  = (const float*)d_in[35]; p.auth_w_u  = (const float*)d_in[36];
  p.xref_g   = (const float*)d_in[37]; p.xref_u   = (const float*)d_in[38];
  p.xlam_g   = (const float*)d_in[39]; p.xlam_u   = (const float*)d_in[40];
  p.xalpha_g = (const float*)d_in[41]; p.xalpha_u = (const float*)d_in[42];
  p.xbeta_g  = (const float*)d_in[43]; p.xbeta_u  = (const float*)d_in[44];
  p.fc1_w = (const float*)d_in[45]; p.fc1_b = (const float*)d_in[46];
  p.fc2_w = (const float*)d_in[47]; p.fc2_b = (const float*)d_in[48];

  float* out = (float*)d_out;
  const int nblocks = in_sizes[0];  // B = 8192
  fused_fwd<<<nblocks, 256, 0, stream>>>(p, out);
}

// Round 3
// 104.031 us; speedup vs baseline: 1.4204x; 1.3813x over previous
//
#include <hip/hip_runtime.h>
#include <math.h>

namespace {

constexpr int NL  = 100;
constexpr int NT  = 20;
constexpr int NDV = 100;
constexpr float KEPS = 1e-8f;

struct Ptrs {
  const int*   user;
  const float* hist_lda;
  const float* hist_vector;
  const float* hist_info;
  const float* hist_authority;
  const float* hist_participants;
  const float* hist_interact;
  const float* timeDelta;
  const float* item_lda;
  const float* item_vector;
  const float* item_info;
  const float* item_authority;
  const float* item_participants;
  const float* item_interact;
  const float* know_lda_pref;
  const float* know_vector_pref;
  const float* lda_gain_ref;
  const float* com_participant_pref;
  const float* td_g;        const float* td_u;
  const float* info_part_g; const float* info_part_u;
  const float* topic_g;     const float* topic_u;
  const float* content_g;   const float* content_u;
  const float* info_w_u;
  const float* inter_apart_g; const float* inter_apart_u;
  const float* auth_apart_g;  const float* auth_apart_u;
  const float* part_w_g;    const float* part_w_u;
  const float* inter_w_g;   const float* inter_w_u;
  const float* auth_w_g;    const float* auth_w_u;
  const float* xref_g;      const float* xref_u;
  const float* xlam_g;      const float* xlam_u;
  const float* xalpha_g;    const float* xalpha_u;
  const float* xbeta_g;     const float* xbeta_u;
  const float* fc1_w; const float* fc1_b;
  const float* fc2_w; const float* fc2_b;
};

// sc[] layout: 0 topic_w, 1 content_w, 2 info_w, 3 part_w, 4 inter_w, 5 auth_w,
//              6 xref, 7 lam, 8 alpha, 9 beta, 10 tdc,
//              11..13 info coef, 14..15 inter coef, 16..18 auth coef
__global__ __launch_bounds__(256)
void fused_fwd(Ptrs p, float* __restrict__ out)
{
  const int b   = blockIdx.x;
  const int tid = threadIdx.x;

  __shared__ __align__(16) float lda_s [101 * NT];
  __shared__ __align__(16) float part_s[101 * NT];
  __shared__ __align__(16) float info_s [304];
  __shared__ __align__(16) float auth_s [304];
  __shared__ __align__(16) float inter_s[202];
  __shared__ __align__(16) float td_s   [100];
  __shared__ __align__(16) float u_lda[NT], u_part[NT], gref[NT];
  __shared__ float dotv_s[101], nnv_s[101];
  __shared__ float sc[19];
  __shared__ float norms[3];
  __shared__ float gw_s[NL];
  __shared__ float cg_s;
  __shared__ float partial_s[12][NT];
  __shared__ float feat_s[3 * NT];

  const int u = p.user[b];
  const float4 fz = make_float4(0.f, 0.f, 0.f, 0.f);

  // ============ 1) ISSUE phase-A vector loads (13 float4 / thread) ============
  const int c      = tid & 31;   // lane in half-wave
  const int rowoff = tid >> 5;   // 0..7
  float4 uv = fz;
  if (c < 25) uv = ((const float4*)(p.know_vector_pref + (size_t)u * NDV))[c];
  const float4* hv4 = (const float4*)(p.hist_vector + (size_t)b * NL * NDV);
  const float4* iv4 = (const float4*)(p.item_vector + (size_t)b * NDV);
  float4 av[13];
  #pragma unroll
  for (int i = 0; i < 13; ++i) {
    const int r = i * 8 + rowoff;
    av[i] = fz;
    if (c < 25 && r <= 100) av[i] = (r < NL) ? hv4[r * 25 + c] : iv4[c];
  }

  // ============ 2) ISSUE big staging loads (reg-staged) ============
  const float4* sl = (const float4*)(p.hist_lda          + (size_t)b * NL * NT);
  const float4* sp = (const float4*)(p.hist_participants + (size_t)b * NL * NT);
  float4 rl0 = sl[tid], rp0 = sp[tid];
  float4 rl1 = fz, rp1 = fz;
  if (tid < 244) { rl1 = sl[tid + 256]; rp1 = sp[tid + 256]; }

  // ============ 3) ISSUE small staging loads (one float4 / thread) ============
  float4 xf = fz;
  if      (tid < 75)  xf = ((const float4*)(p.hist_info      + (size_t)b * 300))[tid];
  else if (tid < 150) xf = ((const float4*)(p.hist_authority + (size_t)b * 300))[tid - 75];
  else if (tid < 200) xf = ((const float4*)(p.hist_interact  + (size_t)b * 200))[tid - 150];
  else if (tid < 225) xf = ((const float4*)(p.timeDelta      + (size_t)b * 100))[tid - 200];
  else if (tid < 230) xf = ((const float4*)(p.item_lda          + (size_t)b * NT))[tid - 225];
  else if (tid < 235) xf = ((const float4*)(p.item_participants + (size_t)b * NT))[tid - 230];
  else if (tid < 240) xf = ((const float4*)(p.know_lda_pref        + (size_t)u * NT))[tid - 235];
  else if (tid < 245) xf = ((const float4*)(p.com_participant_pref + (size_t)u * NT))[tid - 240];
  else if (tid < 250) xf = ((const float4*)(p.lda_gain_ref         + (size_t)u * NT))[tid - 245];
  float e0 = 0.f, e1 = 0.f, e2 = 0.f;
  if (tid == 250) { e0 = p.item_info[(size_t)b*3];      e1 = p.item_info[(size_t)b*3+1];      e2 = p.item_info[(size_t)b*3+2]; }
  else if (tid == 251) { e0 = p.item_authority[(size_t)b*3]; e1 = p.item_authority[(size_t)b*3+1]; e2 = p.item_authority[(size_t)b*3+2]; }
  else if (tid == 252) { e0 = p.item_interact[(size_t)b*2];  e1 = p.item_interact[(size_t)b*2+1]; }

  // norms[0]/norms[2] source loads (threads 253/254)
  float4 nA[5];
  if (tid == 253 || tid == 254) {
    const float* src = (tid == 253 ? p.know_lda_pref : p.com_participant_pref) + (size_t)u * NT;
    #pragma unroll
    for (int j = 0; j < 5; ++j) nA[j] = ((const float4*)src)[j];
  }

  // ============ 4) ISSUE sc loads (19 lanes, branchless pointer selects) ============
  const int  k      = tid - 96;
  const bool has_sc = (k >= 0 && k < 19);
  float g0v = 0.f, u0v = 0.f;
  {
    const int kk = has_sc ? k : 0;
    const float* gp =
      kk==0 ? p.topic_g   : kk==1 ? p.content_g : kk==2 ? p.info_w_u :
      kk==3 ? p.part_w_g  : kk==4 ? p.inter_w_g : kk==5 ? p.auth_w_g :
      kk==6 ? p.xref_g    : kk==7 ? p.xlam_g    : kk==8 ? p.xalpha_g :
      kk==9 ? p.xbeta_g   : kk==10? p.td_g      :
      kk<=13? p.info_part_g : kk<=15? p.inter_apart_g : p.auth_apart_g;
    const float* up =
      kk==0 ? p.topic_u   : kk==1 ? p.content_u : kk==2 ? p.info_w_u :
      kk==3 ? p.part_w_u  : kk==4 ? p.inter_w_u : kk==5 ? p.auth_w_u :
      kk==6 ? p.xref_u    : kk==7 ? p.xlam_u    : kk==8 ? p.xalpha_u :
      kk==9 ? p.xbeta_u   : kk==10? p.td_u      :
      kk<=13? p.info_part_u : kk<=15? p.inter_apart_u : p.auth_apart_u;
    const int go = kk<=10 ? 0 : kk<=13 ? kk-11 : kk<=15 ? kk-14 : kk-16;
    const int uo = kk<=10 ? u : kk<=13 ? u*3+kk-11 : kk<=15 ? u*2+kk-14 : u*3+kk-16;
    if (has_sc) { g0v = gp[go]; u0v = up[uo]; }
  }

  // ============ 5) LDS writes (loads drain here, all were in flight) ============
  ((float4*)lda_s) [tid] = rl0;
  ((float4*)part_s)[tid] = rp0;
  if (tid < 244) { ((float4*)lda_s)[tid + 256] = rl1; ((float4*)part_s)[tid + 256] = rp1; }

  if      (tid < 75)  ((float4*)info_s) [tid]       = xf;
  else if (tid < 150) ((float4*)auth_s) [tid - 75]  = xf;
  else if (tid < 200) ((float4*)inter_s)[tid - 150] = xf;
  else if (tid < 225) ((float4*)td_s)   [tid - 200] = xf;
  else if (tid < 230) ((float4*)lda_s)  [500 + tid - 225] = xf;
  else if (tid < 235) ((float4*)part_s) [500 + tid - 230] = xf;
  else if (tid < 240) ((float4*)u_lda)  [tid - 235] = xf;
  else if (tid < 245) ((float4*)u_part) [tid - 240] = xf;
  else if (tid < 250) ((float4*)gref)   [tid - 245] = xf;
  if      (tid == 250) { info_s[300] = e0; info_s[301] = e1; info_s[302] = e2; }
  else if (tid == 251) { auth_s[300] = e0; auth_s[301] = e1; auth_s[302] = e2; }
  else if (tid == 252) { inter_s[200] = e0; inter_s[201] = e1; }

  if (has_sc) sc[k] = g0v + u0v;

  if (tid == 253 || tid == 254) {
    float s = 0.f;
    #pragma unroll
    for (int j = 0; j < 5; ++j)
      s += nA[j].x*nA[j].x + nA[j].y*nA[j].y + nA[j].z*nA[j].z + nA[j].w*nA[j].w;
    norms[tid == 253 ? 0 : 2] = sqrtf(s);
  }

  // ============ 6) phase-A reduce (shfl) + dotv/nnv to LDS ============
  #pragma unroll
  for (int i = 0; i < 13; ++i) {
    const int r = i * 8 + rowoff;
    float d = uv.x*av[i].x + uv.y*av[i].y + uv.z*av[i].z + uv.w*av[i].w;
    float n = av[i].x*av[i].x + av[i].y*av[i].y + av[i].z*av[i].z + av[i].w*av[i].w;
    #pragma unroll
    for (int m = 1; m < 32; m <<= 1) { d += __shfl_xor(d, m); n += __shfl_xor(n, m); }
    if (c == 0 && r <= 100) { dotv_s[r] = d; nnv_s[r] = n; }
  }
  if (tid < 32) {   // norms[1] from half-wave 0's uv
    float s = uv.x*uv.x + uv.y*uv.y + uv.z*uv.z + uv.w*uv.w;
    #pragma unroll
    for (int m = 1; m < 32; m <<= 1) s += __shfl_xor(s, m);
    if (tid == 0) norms[1] = sqrtf(s);
  }

  __syncthreads();   // the ONLY front-end barrier

  // ============ PHASE B: per-row gains (rows 0..99 hist, 100 item) ============
  if (tid <= 100) {
    const int l = tid;
    const float4* lr4 = (const float4*)&lda_s [l * NT];
    const float4* pr4 = (const float4*)&part_s[l * NT];
    float dot_l = 0.f, nn_l = 0.f, dot_p = 0.f, nn_p = 0.f;
    #pragma unroll
    for (int i = 0; i < 5; ++i) {
      float4 a = lr4[i];
      float4 q = pr4[i];
      dot_l += u_lda[4*i+0]*a.x + u_lda[4*i+1]*a.y + u_lda[4*i+2]*a.z + u_lda[4*i+3]*a.w;
      nn_l  += a.x*a.x + a.y*a.y + a.z*a.z + a.w*a.w;
      dot_p += u_part[4*i+0]*q.x + u_part[4*i+1]*q.y + u_part[4*i+2]*q.z + u_part[4*i+3]*q.w;
      nn_p  += q.x*q.x + q.y*q.y + q.z*q.z + q.w*q.w;
    }
    float lda_gain = dot_l / fmaxf(norms[0] * sqrtf(nn_l), KEPS);
    float part_sim = dot_p / fmaxf(norms[2] * sqrtf(nn_p), KEPS);
    float vec_gain = dotv_s[l] / fmaxf(norms[1] * sqrtf(nnv_s[l]), KEPS);
    float info_gain  = sc[11]*info_s[l*3+0] + sc[12]*info_s[l*3+1] + sc[13]*info_s[l*3+2];
    float inter_gain = sc[14]*inter_s[l*2+0] + sc[15]*inter_s[l*2+1];
    float auth_gain  = sc[16]*auth_s[l*3+0] + sc[17]*auth_s[l*3+1] + sc[18]*auth_s[l*3+2];

    float x = lda_gain*sc[0] + vec_gain*sc[1] + info_gain*sc[2]
            + part_sim*sc[3] + inter_gain*sc[4] + auth_gain*sc[5]
            - sc[6];
    float xa  = fabsf(x);
    bool  pos = (x > 0.f);
    float v   = powf(xa, pos ? sc[8] : sc[9]);
    float gg  = pos ? v : -sc[7] * v;
    if (l < NL) gw_s[l] = gg * expf(-td_s[l] * sc[10]);
    else        cg_s   = gg;
  }
  __syncthreads();

  // ============ PHASE C: hist_topic partials, 12 groups × 20 ============
  if (tid < 240) {
    const int g = tid / NT, t = tid % NT;
    const int l0  = g * 8 + (g < 4 ? g : 4);
    const int cnt = 8 + (g < 4 ? 1 : 0);
    float acc = 0.f;
    for (int j = 0; j < cnt; ++j) acc += lda_s[(l0 + j) * NT + t] * gw_s[l0 + j];
    partial_s[g][t] = acc;
  }
  __syncthreads();

  // ============ PHASE D: features ============
  if (tid < NT) {
    float htop = 0.f;
    #pragma unroll
    for (int g = 0; g < 12; ++g) htop += partial_s[g][tid];
    float diff = gref[tid] - htop;
    float curr = cg_s * lda_s[100 * NT + tid];
    feat_s[tid]          = diff;
    feat_s[NT + tid]     = diff * curr;
    feat_s[2 * NT + tid] = curr;
  }
  __syncthreads();

  // ============ PHASE E: fc1 + fc2 ============
  if (tid < 32) {
    float hp = 0.f;
    if (tid < NT) {
      float acc = p.fc1_b[tid];
      const float* wrow = p.fc1_w + tid * 60;
      #pragma unroll
      for (int kk2 = 0; kk2 < 60; ++kk2) acc += wrow[kk2] * feat_s[kk2];
      hp = acc * p.fc2_w[tid];
    }
    #pragma unroll
    for (int m = 1; m < 32; m <<= 1) hp += __shfl_xor(hp, m);
    if (tid == 0) out[b] = hp + p.fc2_b[0];
  }
}

} // namespace

extern "C" void kernel_launch(void* const* d_in, const int* in_sizes, int n_in,
                              void* d_out, int out_size, void* d_ws, size_t ws_size,
                              hipStream_t stream) {
  Ptrs p;
  p.user              = (const int*)  d_in[0];
  p.hist_lda          = (const float*)d_in[1];
  p.hist_vector       = (const float*)d_in[2];
  p.hist_info         = (const float*)d_in[3];
  p.hist_authority    = (const float*)d_in[4];
  p.hist_participants = (const float*)d_in[5];
  p.hist_interact     = (const float*)d_in[6];
  p.timeDelta         = (const float*)d_in[7];
  p.item_lda          = (const float*)d_in[8];
  p.item_vector       = (const float*)d_in[9];
  p.item_info         = (const float*)d_in[10];
  p.item_authority    = (const float*)d_in[11];
  p.item_participants = (const float*)d_in[12];
  p.item_interact     = (const float*)d_in[13];
  p.know_lda_pref     = (const float*)d_in[14];
  p.know_vector_pref  = (const float*)d_in[15];
  p.lda_gain_ref      = (const float*)d_in[16];
  p.com_participant_pref = (const float*)d_in[17];
  p.td_g   = (const float*)d_in[18];  p.td_u   = (const float*)d_in[19];
  p.info_part_g = (const float*)d_in[20]; p.info_part_u = (const float*)d_in[21];
  p.topic_g   = (const float*)d_in[22]; p.topic_u   = (const float*)d_in[23];
  p.content_g = (const float*)d_in[24]; p.content_u = (const float*)d_in[25];
  p.info_w_u  = (const float*)d_in[26];
  p.inter_apart_g = (const float*)d_in[27]; p.inter_apart_u = (const float*)d_in[28];
  p.auth_apart_g  = (const float*)d_in[29]; p.auth_apart_u  = (const float*)d_in[30];
  p.part_w_g  = (const float*)d_in[31]; p.part_w_u  = (const float*)d_in[32];
  p.inter_w_g = (const float*)d_in[33]; p.inter_w_u = (const float*)d_in[34];
  p.auth_w_g  = (const float*)d_in[35]; p.auth_w_u  = (const float*)d_in[36];
  p.xref_g   = (const float*)d_in[37]; p.xref_u   = (const float*)d_in[38];
  p.xlam_g   = (const float*)d_in[39]; p.xlam_u   = (const float*)d_in[40];
  p.xalpha_g = (const float*)d_in[41]; p.xalpha_u = (const float*)d_in[42];
  p.xbeta_g  = (const float*)d_in[43]; p.xbeta_u  = (const float*)d_in[44];
  p.fc1_w = (const float*)d_in[45]; p.fc1_b = (const float*)d_in[46];
  p.fc2_w = (const float*)d_in[47]; p.fc2_b = (const float*)d_in[48];

  float* out = (float*)d_out;
  const int nblocks = in_sizes[0];  // B = 8192
  fused_fwd<<<nblocks, 256, 0, stream>>>(p, out);
}